// Round 1
// baseline (2212.958 us; speedup 1.0000x reference)
//
#include <hip/hip_runtime.h>
#include <math.h>

#define NV 20000
#define NE 100000
#define DD 32
#define NG 1000
#define NDEPTH 3
#define S2S 6
#define NB 8   // nodes per block in k_nodeA

__device__ __forceinline__ float sigmoidf_(float x) { return 1.0f / (1.0f + __expf(-x)); }

// ---------------- embeddings ----------------
__global__ void k_embed_node(const float* __restrict__ node, const float* __restrict__ Wn,
                             const float* __restrict__ bn, float* __restrict__ h,
                             float* __restrict__ h0) {
    __shared__ float sW[36 * DD];
    __shared__ float sb[DD];
    for (int i = threadIdx.x; i < 36 * DD; i += blockDim.x) sW[i] = Wn[i];
    if (threadIdx.x < DD) sb[threadIdx.x] = bn[threadIdx.x];
    __syncthreads();
    int v = blockIdx.x * blockDim.x + threadIdx.x;
    if (v >= NV) return;
    float x[36];
    #pragma unroll
    for (int i = 0; i < 36; ++i) x[i] = node[v * 36 + i];
    #pragma unroll 4
    for (int f = 0; f < DD; ++f) {
        float acc = sb[f];
        #pragma unroll
        for (int i = 0; i < 36; ++i) acc += x[i] * sW[i * DD + f];
        float y = acc > 0.f ? acc : 0.01f * acc;
        h[v * DD + f] = y;
        h0[v * DD + f] = y;
    }
}

__global__ void k_embed_edge(const float* __restrict__ edge, const float* __restrict__ We,
                             const float* __restrict__ be, float* __restrict__ e_h) {
    __shared__ float sW[12 * DD];
    __shared__ float sb[DD];
    for (int i = threadIdx.x; i < 12 * DD; i += blockDim.x) sW[i] = We[i];
    if (threadIdx.x < DD) sb[threadIdx.x] = be[threadIdx.x];
    __syncthreads();
    int e = blockIdx.x * blockDim.x + threadIdx.x;
    if (e >= NE) return;
    float x[12];
    #pragma unroll
    for (int i = 0; i < 12; ++i) x[i] = edge[e * 12 + i];
    #pragma unroll 4
    for (int f = 0; f < DD; ++f) {
        float acc = sb[f];
        #pragma unroll
        for (int i = 0; i < 12; ++i) acc += x[i] * sW[i * DD + f];
        float y = acc > 0.f ? acc : 0.01f * acc;
        e_h[(size_t)e * DD + f] = y;
    }
}

// ---------------- per-layer edge hidden: t = relu(e_h @ eW1 + eb1), (E,64) ----------------
__global__ void k_edge_t(const float* __restrict__ e_h, const float* __restrict__ eW1,
                         const float* __restrict__ eb1, float* __restrict__ t) {
    __shared__ float sW[DD * 64];
    __shared__ float sb[64];
    for (int i = threadIdx.x; i < DD * 64; i += blockDim.x) sW[i] = eW1[i];
    if (threadIdx.x < 64) sb[threadIdx.x] = eb1[threadIdx.x];
    __syncthreads();
    int e = blockIdx.x * blockDim.x + threadIdx.x;
    if (e >= NE) return;
    float x[DD];
    #pragma unroll
    for (int d = 0; d < DD; ++d) x[d] = e_h[(size_t)e * DD + d];
    for (int k = 0; k < 64; ++k) {
        float acc = sb[k];
        #pragma unroll
        for (int d = 0; d < DD; ++d) acc += x[d] * sW[d * 64 + k];
        t[(size_t)e * 64 + k] = fmaxf(acc, 0.f);
    }
}

// ---------------- per-layer node factor: A[v][k*32+f] = sum_d h[v][d]*eW2[k*1024+d*32+f] ----------------
// Also bb[v][f] = sum_d h[v][d]*eb2[d*32+f]
__global__ void k_nodeA(const float* __restrict__ h, const float* __restrict__ eW2,
                        const float* __restrict__ eb2, float* __restrict__ A,
                        float* __restrict__ bb) {
    int v0 = blockIdx.x * NB;
    __shared__ float sh[NB][DD];
    int tid = threadIdx.x;
    sh[tid >> 5][tid & 31] = h[(size_t)(v0 + (tid >> 5)) * DD + (tid & 31)];
    __syncthreads();
    float acc[8][NB];
    #pragma unroll
    for (int jj = 0; jj < 8; ++jj)
        #pragma unroll
        for (int n = 0; n < NB; ++n) acc[jj][n] = 0.f;
    for (int d = 0; d < DD; ++d) {
        float hs[NB];
        #pragma unroll
        for (int n = 0; n < NB; ++n) hs[n] = sh[n][d];
        #pragma unroll
        for (int jj = 0; jj < 8; ++jj) {
            int j = tid + jj * 256;
            int k = j >> 5, f = j & 31;
            float w = eW2[k * 1024 + d * 32 + f];
            #pragma unroll
            for (int n = 0; n < NB; ++n) acc[jj][n] += hs[n] * w;
        }
    }
    #pragma unroll
    for (int jj = 0; jj < 8; ++jj)
        #pragma unroll
        for (int n = 0; n < NB; ++n)
            A[(size_t)(v0 + n) * 2048 + tid + jj * 256] = acc[jj][n];
    // bias factor
    int n = tid >> 5, f = tid & 31;
    float bacc = 0.f;
    #pragma unroll
    for (int d = 0; d < DD; ++d) bacc += sh[n][d] * eb2[d * 32 + f];
    bb[(size_t)(v0 + n) * DD + f] = bacc;
}

// ---------------- message + scatter: half-wave (32 lanes) per edge ----------------
__global__ void k_msg(const float* __restrict__ t, const float* __restrict__ A,
                      const float* __restrict__ bb, const int* __restrict__ src,
                      const int* __restrict__ dst, float* __restrict__ agg) {
    int gid = blockIdx.x * blockDim.x + threadIdx.x;
    int e = gid >> 5;
    int f = gid & 31;
    if (e >= NE) return;
    int s = src[e], dn = dst[e];
    const float* Ap = A + (size_t)s * 2048 + f;
    const float* tp = t + (size_t)e * 64;
    float acc = bb[(size_t)s * DD + f];
    #pragma unroll
    for (int k = 0; k < 64; ++k) acc += tp[k] * Ap[k * 32];
    atomicAdd(&agg[(size_t)dn * DD + f], acc);
}

// ---------------- GRU (vs hidden0) + LayerNorm ----------------
__global__ void k_gru_ln(const float* __restrict__ agg, const float* __restrict__ h0,
                         const float* __restrict__ wih, const float* __restrict__ whh,
                         const float* __restrict__ bih, const float* __restrict__ bhh,
                         const float* __restrict__ lng, const float* __restrict__ lnb,
                         float* __restrict__ h) {
    __shared__ float sWih[96 * DD];
    __shared__ float sWhh[96 * DD];
    __shared__ float sbih[96], sbhh[96], sg[DD], sb[DD];
    for (int i = threadIdx.x; i < 96 * DD; i += blockDim.x) { sWih[i] = wih[i]; sWhh[i] = whh[i]; }
    if (threadIdx.x < 96) { sbih[threadIdx.x] = bih[threadIdx.x]; sbhh[threadIdx.x] = bhh[threadIdx.x]; }
    if (threadIdx.x < DD) { sg[threadIdx.x] = lng[threadIdx.x]; sb[threadIdx.x] = lnb[threadIdx.x]; }
    __syncthreads();
    int v = blockIdx.x * blockDim.x + threadIdx.x;
    if (v >= NV) return;
    float a[DD], h0v[DD], hnew[DD];
    #pragma unroll
    for (int f = 0; f < DD; ++f) {
        a[f] = fmaxf(agg[(size_t)v * DD + f], 0.f);
        h0v[f] = h0[(size_t)v * DD + f];
    }
    for (int j = 0; j < DD; ++j) {
        float gir = sbih[j], giz = sbih[DD + j], gin = sbih[2 * DD + j];
        float ghr = sbhh[j], ghz = sbhh[DD + j], ghn = sbhh[2 * DD + j];
        #pragma unroll
        for (int f = 0; f < DD; ++f) {
            gir += a[f] * sWih[j * DD + f];
            giz += a[f] * sWih[(DD + j) * DD + f];
            gin += a[f] * sWih[(2 * DD + j) * DD + f];
            ghr += h0v[f] * sWhh[j * DD + f];
            ghz += h0v[f] * sWhh[(DD + j) * DD + f];
            ghn += h0v[f] * sWhh[(2 * DD + j) * DD + f];
        }
        float r = sigmoidf_(gir + ghr);
        float z = sigmoidf_(giz + ghz);
        float n = tanhf(gin + r * ghn);
        hnew[j] = (1.f - z) * n + z * h0v[j];
    }
    float mu = 0.f;
    #pragma unroll
    for (int j = 0; j < DD; ++j) mu += hnew[j];
    mu *= (1.f / DD);
    float var = 0.f;
    #pragma unroll
    for (int j = 0; j < DD; ++j) { float d = hnew[j] - mu; var += d * d; }
    var *= (1.f / DD);
    float inv = rsqrtf(var + 1e-5f);
    #pragma unroll
    for (int j = 0; j < DD; ++j)
        h[(size_t)v * DD + j] = (hnew[j] - mu) * inv * sg[j] + sb[j];
}

// ---------------- graph boundaries (node2graph is sorted) ----------------
__global__ void k_bounds(const int* __restrict__ n2g, int* __restrict__ gstart) {
    int g = blockIdx.x * blockDim.x + threadIdx.x;
    if (g > NG) return;
    int lo = 0, hi = NV;
    while (lo < hi) {
        int mid = (lo + hi) >> 1;
        if (n2g[mid] < g) lo = mid + 1; else hi = mid;
    }
    gstart[g] = lo;
}

// ---------------- fused Set2Set (6 iters) + prediction MLP, one wave per graph ----------------
__global__ void k_s2s(const float* __restrict__ h, const int* __restrict__ gstart,
                      const float* __restrict__ wih, const float* __restrict__ whh,
                      const float* __restrict__ bih, const float* __restrict__ bhh,
                      const float* __restrict__ Wp1, const float* __restrict__ bp1,
                      const float* __restrict__ Wp2, const float* __restrict__ bp2,
                      float* __restrict__ out) {
    int g = blockIdx.x;
    int lane = threadIdx.x;   // 0..63
    int s = gstart[g], e = gstart[g + 1];
    __shared__ float qs[64];
    __shared__ float hhs[DD], ccs[DD], gbuf[128], rr[DD];
    qs[lane] = 0.f;
    if (lane < DD) { hhs[lane] = 0.f; ccs[lane] = 0.f; }
    __syncthreads();
    for (int it = 0; it < S2S; ++it) {
        // LSTM gates: lane computes gates j=lane and j=lane+64
        float g0 = bih[lane] + bhh[lane];
        float g1 = bih[lane + 64] + bhh[lane + 64];
        for (int p = 0; p < 64; ++p) {
            float q = qs[p];
            g0 += q * wih[lane * 64 + p];
            g1 += q * wih[(lane + 64) * 64 + p];
        }
        for (int p = 0; p < DD; ++p) {
            float hp = hhs[p];
            g0 += hp * whh[lane * DD + p];
            g1 += hp * whh[(lane + 64) * DD + p];
        }
        gbuf[lane] = g0;
        gbuf[lane + 64] = g1;
        __syncthreads();
        if (lane < DD) {
            float ii = gbuf[lane], ff = gbuf[DD + lane], gg = gbuf[2 * DD + lane], oo = gbuf[3 * DD + lane];
            float c = sigmoidf_(ff) * ccs[lane] + sigmoidf_(ii) * tanhf(gg);
            ccs[lane] = c;
            hhs[lane] = sigmoidf_(oo) * tanhf(c);
        }
        __syncthreads();
        // attention over this graph's nodes (both 32-lane halves compute identically)
        int f = lane & 31;
        float qf = hhs[f];
        float m = -1e30f, ssum = 0.f;
        for (int v = s; v < e; ++v) {
            float p = h[(size_t)v * DD + f] * qf;
            #pragma unroll
            for (int o = 16; o; o >>= 1) p += __shfl_xor(p, o, 64);
            float nm = fmaxf(m, p);
            ssum = ssum * __expf(m - nm) + __expf(p - nm);
            m = nm;
        }
        float r = 0.f;
        for (int v = s; v < e; ++v) {
            float hv = h[(size_t)v * DD + f];
            float p = hv * qf;
            #pragma unroll
            for (int o = 16; o; o >>= 1) p += __shfl_xor(p, o, 64);
            r += __expf(p - m) * hv;
        }
        r = (e > s) ? (r / ssum) : 0.f;
        if (lane < DD) rr[lane] = r;
        __syncthreads();
        qs[lane] = (lane < DD) ? hhs[lane] : rr[lane - DD];
        __syncthreads();
    }
    // prediction MLP: out = relu(q_star @ Wp1 + bp1) @ Wp2 + bp2
    int f = lane & 31;
    float u = bp1[f];
    for (int p = 0; p < 64; ++p) u += qs[p] * Wp1[p * DD + f];
    u = fmaxf(u, 0.f);
    float pr = u * Wp2[f];
    #pragma unroll
    for (int o = 16; o; o >>= 1) pr += __shfl_xor(pr, o, 64);
    if (lane == 0) out[g] = pr + bp2[0];
}

extern "C" void kernel_launch(void* const* d_in, const int* in_sizes, int n_in,
                              void* d_out, int out_size, void* d_ws, size_t ws_size,
                              hipStream_t stream) {
    const float* node = (const float*)d_in[0];
    const float* edge = (const float*)d_in[1];
    const int*   src  = (const int*)d_in[2];
    const int*   dst  = (const int*)d_in[3];
    const int*   n2g  = (const int*)d_in[4];
    const float* Wn   = (const float*)d_in[5];
    const float* bn   = (const float*)d_in[6];
    const float* We   = (const float*)d_in[7];
    const float* be   = (const float*)d_in[8];
    const float* eW1  = (const float*)d_in[9];
    const float* eb1  = (const float*)d_in[10];
    const float* eW2  = (const float*)d_in[11];
    const float* eb2  = (const float*)d_in[12];
    const float* gwih = (const float*)d_in[13];
    const float* gwhh = (const float*)d_in[14];
    const float* gbih = (const float*)d_in[15];
    const float* gbhh = (const float*)d_in[16];
    const float* lng  = (const float*)d_in[17];
    const float* lnb  = (const float*)d_in[18];
    const float* lwih = (const float*)d_in[19];
    const float* lwhh = (const float*)d_in[20];
    const float* lbih = (const float*)d_in[21];
    const float* lbhh = (const float*)d_in[22];
    const float* Wp1  = (const float*)d_in[23];
    const float* bp1  = (const float*)d_in[24];
    const float* Wp2  = (const float*)d_in[25];
    const float* bp2  = (const float*)d_in[26];

    float* ws = (float*)d_ws;
    float* h    = ws; ws += (size_t)NV * DD;
    float* h0   = ws; ws += (size_t)NV * DD;
    float* e_h  = ws; ws += (size_t)NE * DD;
    float* t    = ws; ws += (size_t)NE * 64;
    float* bb   = ws; ws += (size_t)NV * DD;
    float* agg  = ws; ws += (size_t)NV * DD;
    int* gstart = (int*)ws; ws += (NG + 2);
    float* A    = ws; ws += (size_t)NV * 2048;   // 164 MB, reused across layers

    k_embed_node<<<(NV + 255) / 256, 256, 0, stream>>>(node, Wn, bn, h, h0);
    k_embed_edge<<<(NE + 255) / 256, 256, 0, stream>>>(edge, We, be, e_h);
    k_bounds<<<(NG + 256) / 256, 256, 0, stream>>>(n2g, gstart);

    for (int l = 0; l < NDEPTH; ++l) {
        k_edge_t<<<(NE + 255) / 256, 256, 0, stream>>>(e_h, eW1 + (size_t)l * DD * 64, eb1 + l * 64, t);
        k_nodeA<<<NV / NB, 256, 0, stream>>>(h, eW2 + (size_t)l * 64 * 1024, eb2 + l * 1024, A, bb);
        hipMemsetAsync(agg, 0, (size_t)NV * DD * sizeof(float), stream);
        k_msg<<<((size_t)NE * 32 + 255) / 256, 256, 0, stream>>>(t, A, bb, src, dst, agg);
        k_gru_ln<<<(NV + 255) / 256, 256, 0, stream>>>(agg, h0,
                                                       gwih + (size_t)l * 96 * DD, gwhh + (size_t)l * 96 * DD,
                                                       gbih + l * 96, gbhh + l * 96,
                                                       lng + l * DD, lnb + l * DD, h);
    }

    k_s2s<<<NG, 64, 0, stream>>>(h, gstart, lwih, lwhh, lbih, lbhh, Wp1, bp1, Wp2, bp2, (float*)d_out);
}

// Round 2
// 1321.137 us; speedup vs baseline: 1.6750x; 1.6750x over previous
//
#include <hip/hip_runtime.h>
#include <math.h>

#define NV 20000
#define NE 100000
#define DD 32
#define NG 1000
#define NDEPTH 3
#define S2S 6
#define NB 8     // nodes per block in k_nodeA
#define EPB 16   // edges per block in k_edge_t

__device__ __forceinline__ float sigmoidf_(float x) { return 1.0f / (1.0f + __expf(-x)); }

// ---------------- node embedding: 32 nodes/block, 256 threads = 8 slots x 32 f, 4 node-groups ----------------
__global__ void k_embed_node(const float* __restrict__ node, const float* __restrict__ Wn,
                             const float* __restrict__ bn, float* __restrict__ h,
                             float* __restrict__ h0) {
    __shared__ float sW[36 * DD];
    __shared__ float sb[DD];
    __shared__ float sx[32][36];
    int tid = threadIdx.x;
    for (int i = tid; i < 36 * DD; i += 256) sW[i] = Wn[i];
    if (tid < DD) sb[tid] = bn[tid];
    int v0 = blockIdx.x * 32;
    for (int i = tid; i < 32 * 36; i += 256) sx[i / 36][i % 36] = node[(size_t)v0 * 36 + i];
    __syncthreads();
    int f = tid & 31;
    int nb = tid >> 5;
    for (int g = 0; g < 4; ++g) {
        int n = nb + 8 * g;
        float acc = sb[f];
        #pragma unroll
        for (int i = 0; i < 36; ++i) acc += sx[n][i] * sW[i * DD + f];
        float y = acc > 0.f ? acc : 0.01f * acc;
        h[(size_t)(v0 + n) * DD + f] = y;
        h0[(size_t)(v0 + n) * DD + f] = y;
    }
}

// ---------------- edge embedding: 32 edges/block ----------------
__global__ void k_embed_edge(const float* __restrict__ edge, const float* __restrict__ We,
                             const float* __restrict__ be, float* __restrict__ e_h) {
    __shared__ float sW[12 * DD];
    __shared__ float sb[DD];
    __shared__ float sx[32][12];
    int tid = threadIdx.x;
    for (int i = tid; i < 12 * DD; i += 256) sW[i] = We[i];
    if (tid < DD) sb[tid] = be[tid];
    int e0 = blockIdx.x * 32;
    for (int i = tid; i < 32 * 12; i += 256) sx[i / 12][i % 12] = edge[(size_t)e0 * 12 + i];
    __syncthreads();
    int f = tid & 31;
    int nb = tid >> 5;
    for (int g = 0; g < 4; ++g) {
        int n = nb + 8 * g;
        float acc = sb[f];
        #pragma unroll
        for (int i = 0; i < 12; ++i) acc += sx[n][i] * sW[i * DD + f];
        float y = acc > 0.f ? acc : 0.01f * acc;
        e_h[(size_t)(e0 + n) * DD + f] = y;
    }
}

// ---------------- per-layer edge hidden: t = relu(e_h @ eW1 + eb1), (E,64) ----------------
// 16 edges/block; 256 threads = 4 edge-slots x 64 gates; 4 edge-groups per thread.
__global__ void k_edge_t(const float* __restrict__ e_h, const float* __restrict__ eW1,
                         const float* __restrict__ eb1, float* __restrict__ t) {
    __shared__ float sW[DD * 64];
    __shared__ float sb[64];
    __shared__ float sx[EPB][DD];
    int tid = threadIdx.x;
    for (int i = tid; i < DD * 64; i += 256) sW[i] = eW1[i];
    if (tid < 64) sb[tid] = eb1[tid];
    int e0 = blockIdx.x * EPB;
    for (int i = tid; i < EPB * DD; i += 256) sx[i >> 5][i & 31] = e_h[(size_t)e0 * DD + i];
    __syncthreads();
    int k = tid & 63;
    int nb = tid >> 6;
    for (int g = 0; g < 4; ++g) {
        int n = nb + 4 * g;
        float acc = sb[k];
        #pragma unroll
        for (int d0 = 0; d0 < DD; ++d0) {
            int d = (k + d0) & 31;          // rotated start: conflict-free banks
            acc += sx[n][d] * sW[d * 64 + k];
        }
        t[(size_t)(e0 + n) * 64 + k] = fmaxf(acc, 0.f);
    }
}

// ---------------- per-layer node factor: A[v][k*32+f] = sum_d h[v][d]*eW2[k*1024+d*32+f] ----------------
__global__ void k_nodeA(const float* __restrict__ h, const float* __restrict__ eW2,
                        const float* __restrict__ eb2, float* __restrict__ A,
                        float* __restrict__ bb) {
    int v0 = blockIdx.x * NB;
    __shared__ float sh[NB][DD];
    int tid = threadIdx.x;
    sh[tid >> 5][tid & 31] = h[(size_t)(v0 + (tid >> 5)) * DD + (tid & 31)];
    __syncthreads();
    float acc[8][NB];
    #pragma unroll
    for (int jj = 0; jj < 8; ++jj)
        #pragma unroll
        for (int n = 0; n < NB; ++n) acc[jj][n] = 0.f;
    for (int d = 0; d < DD; ++d) {
        float hs[NB];
        #pragma unroll
        for (int n = 0; n < NB; ++n) hs[n] = sh[n][d];
        #pragma unroll
        for (int jj = 0; jj < 8; ++jj) {
            int j = tid + jj * 256;
            float w = eW2[(j >> 5) * 1024 + d * 32 + (j & 31)];
            #pragma unroll
            for (int n = 0; n < NB; ++n) acc[jj][n] += hs[n] * w;
        }
    }
    #pragma unroll
    for (int jj = 0; jj < 8; ++jj)
        #pragma unroll
        for (int n = 0; n < NB; ++n)
            A[(size_t)(v0 + n) * 2048 + tid + jj * 256] = acc[jj][n];
    int n = tid >> 5, f = tid & 31;
    float bacc = 0.f;
    #pragma unroll
    for (int d = 0; d < DD; ++d) bacc += sh[n][d] * eb2[d * 32 + f];
    bb[(size_t)(v0 + n) * DD + f] = bacc;
}

// ---------------- message + scatter: half-wave (32 lanes) per edge ----------------
__global__ void k_msg(const float* __restrict__ t, const float* __restrict__ A,
                      const float* __restrict__ bb, const int* __restrict__ src,
                      const int* __restrict__ dst, float* __restrict__ agg) {
    int gid = blockIdx.x * blockDim.x + threadIdx.x;
    int e = gid >> 5;
    int f = gid & 31;
    if (e >= NE) return;
    int s = src[e], dn = dst[e];
    const float* Ap = A + (size_t)s * 2048 + f;
    const float* tp = t + (size_t)e * 64;
    float acc = bb[(size_t)s * DD + f];
    #pragma unroll
    for (int k = 0; k < 64; ++k) acc += tp[k] * Ap[k * 32];
    atomicAdd(&agg[(size_t)dn * DD + f], acc);
}

// ---------------- GRU (vs hidden0) + LayerNorm: 32 nodes/block ----------------
// 256 threads = 8 node-slots x 32 gate-outputs; 4 node-groups per thread.
__global__ void k_gru_ln(const float* __restrict__ agg, const float* __restrict__ h0,
                         const float* __restrict__ wih, const float* __restrict__ whh,
                         const float* __restrict__ bih, const float* __restrict__ bhh,
                         const float* __restrict__ lng, const float* __restrict__ lnb,
                         float* __restrict__ h) {
    __shared__ float sWih[96 * DD];
    __shared__ float sWhh[96 * DD];
    __shared__ float sbih[96], sbhh[96], sg[DD], sb[DD];
    __shared__ float sA[32][DD], sH[32][DD];
    int tid = threadIdx.x;
    for (int i = tid; i < 96 * DD; i += 256) { sWih[i] = wih[i]; sWhh[i] = whh[i]; }
    if (tid < 96) { sbih[tid] = bih[tid]; sbhh[tid] = bhh[tid]; }
    if (tid < DD) { sg[tid] = lng[tid]; sb[tid] = lnb[tid]; }
    int v0 = blockIdx.x * 32;
    for (int i = tid; i < 32 * DD; i += 256) {
        sA[i >> 5][i & 31] = fmaxf(agg[(size_t)v0 * DD + i], 0.f);
        sH[i >> 5][i & 31] = h0[(size_t)v0 * DD + i];
    }
    __syncthreads();
    int j = tid & 31;
    int nb = tid >> 5;
    float b_ir = sbih[j], b_iz = sbih[DD + j], b_in = sbih[2 * DD + j];
    float b_hr = sbhh[j], b_hz = sbhh[DD + j], b_hn = sbhh[2 * DD + j];
    float lg = sg[j], lb = sb[j];
    for (int g = 0; g < 4; ++g) {
        int n = nb + 8 * g;
        float gir = b_ir, giz = b_iz, gin = b_in;
        float ghr = b_hr, ghz = b_hz, ghn = b_hn;
        #pragma unroll
        for (int f0 = 0; f0 < DD; ++f0) {
            int f = (j + f0) & 31;          // rotated: conflict-free weight banks
            float a = sA[n][f], hh = sH[n][f];
            gir += a * sWih[j * DD + f];
            giz += a * sWih[(DD + j) * DD + f];
            gin += a * sWih[(2 * DD + j) * DD + f];
            ghr += hh * sWhh[j * DD + f];
            ghz += hh * sWhh[(DD + j) * DD + f];
            ghn += hh * sWhh[(2 * DD + j) * DD + f];
        }
        float r = sigmoidf_(gir + ghr);
        float z = sigmoidf_(giz + ghz);
        float nn = tanhf(gin + r * ghn);
        float hnew = (1.f - z) * nn + z * sH[n][j];
        // LayerNorm across the 32 lanes sharing this node (xor <=16 stays in half-wave)
        float mu = hnew;
        #pragma unroll
        for (int o = 16; o; o >>= 1) mu += __shfl_xor(mu, o, 64);
        mu *= (1.f / DD);
        float d = hnew - mu;
        float var = d * d;
        #pragma unroll
        for (int o = 16; o; o >>= 1) var += __shfl_xor(var, o, 64);
        var *= (1.f / DD);
        float inv = rsqrtf(var + 1e-5f);
        h[(size_t)(v0 + n) * DD + j] = d * inv * lg + lb;
    }
}

// ---------------- graph boundaries (node2graph is sorted) ----------------
__global__ void k_bounds(const int* __restrict__ n2g, int* __restrict__ gstart) {
    int g = blockIdx.x * blockDim.x + threadIdx.x;
    if (g > NG) return;
    int lo = 0, hi = NV;
    while (lo < hi) {
        int mid = (lo + hi) >> 1;
        if (n2g[mid] < g) lo = mid + 1; else hi = mid;
    }
    gstart[g] = lo;
}

// ---------------- fused Set2Set (6 iters) + prediction MLP, one wave per graph ----------------
__global__ void k_s2s(const float* __restrict__ h, const int* __restrict__ gstart,
                      const float* __restrict__ wih, const float* __restrict__ whh,
                      const float* __restrict__ bih, const float* __restrict__ bhh,
                      const float* __restrict__ Wp1, const float* __restrict__ bp1,
                      const float* __restrict__ Wp2, const float* __restrict__ bp2,
                      float* __restrict__ out) {
    int g = blockIdx.x;
    int lane = threadIdx.x;   // 0..63
    int s = gstart[g], e = gstart[g + 1];
    __shared__ float qs[64];
    __shared__ float hhs[DD], ccs[DD], gbuf[128], rr[DD];
    qs[lane] = 0.f;
    if (lane < DD) { hhs[lane] = 0.f; ccs[lane] = 0.f; }
    __syncthreads();
    for (int it = 0; it < S2S; ++it) {
        float g0 = bih[lane] + bhh[lane];
        float g1 = bih[lane + 64] + bhh[lane + 64];
        for (int p = 0; p < 64; ++p) {
            float q = qs[p];
            g0 += q * wih[lane * 64 + p];
            g1 += q * wih[(lane + 64) * 64 + p];
        }
        for (int p = 0; p < DD; ++p) {
            float hp = hhs[p];
            g0 += hp * whh[lane * DD + p];
            g1 += hp * whh[(lane + 64) * DD + p];
        }
        gbuf[lane] = g0;
        gbuf[lane + 64] = g1;
        __syncthreads();
        if (lane < DD) {
            float ii = gbuf[lane], ff = gbuf[DD + lane], gg = gbuf[2 * DD + lane], oo = gbuf[3 * DD + lane];
            float c = sigmoidf_(ff) * ccs[lane] + sigmoidf_(ii) * tanhf(gg);
            ccs[lane] = c;
            hhs[lane] = sigmoidf_(oo) * tanhf(c);
        }
        __syncthreads();
        int f = lane & 31;
        float qf = hhs[f];
        float m = -1e30f, ssum = 0.f;
        for (int v = s; v < e; ++v) {
            float p = h[(size_t)v * DD + f] * qf;
            #pragma unroll
            for (int o = 16; o; o >>= 1) p += __shfl_xor(p, o, 64);
            float nm = fmaxf(m, p);
            ssum = ssum * __expf(m - nm) + __expf(p - nm);
            m = nm;
        }
        float r = 0.f;
        for (int v = s; v < e; ++v) {
            float hv = h[(size_t)v * DD + f];
            float p = hv * qf;
            #pragma unroll
            for (int o = 16; o; o >>= 1) p += __shfl_xor(p, o, 64);
            r += __expf(p - m) * hv;
        }
        r = (e > s) ? (r / ssum) : 0.f;
        if (lane < DD) rr[lane] = r;
        __syncthreads();
        qs[lane] = (lane < DD) ? hhs[lane] : rr[lane - DD];
        __syncthreads();
    }
    int f = lane & 31;
    float u = bp1[f];
    for (int p = 0; p < 64; ++p) u += qs[p] * Wp1[p * DD + f];
    u = fmaxf(u, 0.f);
    float pr = u * Wp2[f];
    #pragma unroll
    for (int o = 16; o; o >>= 1) pr += __shfl_xor(pr, o, 64);
    if (lane == 0) out[g] = pr + bp2[0];
}

extern "C" void kernel_launch(void* const* d_in, const int* in_sizes, int n_in,
                              void* d_out, int out_size, void* d_ws, size_t ws_size,
                              hipStream_t stream) {
    const float* node = (const float*)d_in[0];
    const float* edge = (const float*)d_in[1];
    const int*   src  = (const int*)d_in[2];
    const int*   dst  = (const int*)d_in[3];
    const int*   n2g  = (const int*)d_in[4];
    const float* Wn   = (const float*)d_in[5];
    const float* bn   = (const float*)d_in[6];
    const float* We   = (const float*)d_in[7];
    const float* be   = (const float*)d_in[8];
    const float* eW1  = (const float*)d_in[9];
    const float* eb1  = (const float*)d_in[10];
    const float* eW2  = (const float*)d_in[11];
    const float* eb2  = (const float*)d_in[12];
    const float* gwih = (const float*)d_in[13];
    const float* gwhh = (const float*)d_in[14];
    const float* gbih = (const float*)d_in[15];
    const float* gbhh = (const float*)d_in[16];
    const float* lng  = (const float*)d_in[17];
    const float* lnb  = (const float*)d_in[18];
    const float* lwih = (const float*)d_in[19];
    const float* lwhh = (const float*)d_in[20];
    const float* lbih = (const float*)d_in[21];
    const float* lbhh = (const float*)d_in[22];
    const float* Wp1  = (const float*)d_in[23];
    const float* bp1  = (const float*)d_in[24];
    const float* Wp2  = (const float*)d_in[25];
    const float* bp2  = (const float*)d_in[26];

    float* ws = (float*)d_ws;
    float* h    = ws; ws += (size_t)NV * DD;
    float* h0   = ws; ws += (size_t)NV * DD;
    float* e_h  = ws; ws += (size_t)NE * DD;
    float* t    = ws; ws += (size_t)NE * 64;
    float* bb   = ws; ws += (size_t)NV * DD;
    float* agg  = ws; ws += (size_t)NV * DD;
    int* gstart = (int*)ws; ws += (NG + 2);
    float* A    = ws; ws += (size_t)NV * 2048;   // 164 MB, reused across layers

    k_embed_node<<<(NV + 31) / 32, 256, 0, stream>>>(node, Wn, bn, h, h0);
    k_embed_edge<<<(NE + 31) / 32, 256, 0, stream>>>(edge, We, be, e_h);
    k_bounds<<<(NG + 256) / 256, 256, 0, stream>>>(n2g, gstart);

    for (int l = 0; l < NDEPTH; ++l) {
        k_edge_t<<<NE / EPB, 256, 0, stream>>>(e_h, eW1 + (size_t)l * DD * 64, eb1 + l * 64, t);
        k_nodeA<<<NV / NB, 256, 0, stream>>>(h, eW2 + (size_t)l * 64 * 1024, eb2 + l * 1024, A, bb);
        hipMemsetAsync(agg, 0, (size_t)NV * DD * sizeof(float), stream);
        k_msg<<<((size_t)NE * 32 + 255) / 256, 256, 0, stream>>>(t, A, bb, src, dst, agg);
        k_gru_ln<<<NV / 32, 256, 0, stream>>>(agg, h0,
                                              gwih + (size_t)l * 96 * DD, gwhh + (size_t)l * 96 * DD,
                                              gbih + l * 96, gbhh + l * 96,
                                              lng + l * DD, lnb + l * DD, h);
    }

    k_s2s<<<NG, 64, 0, stream>>>(h, gstart, lwih, lwhh, lbih, lbhh, Wp1, bp1, Wp2, bp2, (float*)d_out);
}

// Round 3
// 1022.519 us; speedup vs baseline: 2.1642x; 1.2920x over previous
//
#include <hip/hip_runtime.h>
#include <math.h>

#define NV 20000
#define NE 100000
#define DD 32
#define NG 1000
#define NDEPTH 3
#define S2S 6
#define NBK 8    // src-nodes per block in k_fused
#define EPB 16   // edges per block in k_edge_t
#define SCAN_T 256
#define SCAN_C 80  // 256*80 = 20480 >= NV

__device__ __forceinline__ float sigmoidf_(float x) { return 1.0f / (1.0f + __expf(-x)); }

// ---------------- node embedding ----------------
__global__ void k_embed_node(const float* __restrict__ node, const float* __restrict__ Wn,
                             const float* __restrict__ bn, float* __restrict__ h,
                             float* __restrict__ h0) {
    __shared__ float sW[36 * DD];
    __shared__ float sb[DD];
    __shared__ float sx[32][36];
    int tid = threadIdx.x;
    for (int i = tid; i < 36 * DD; i += 256) sW[i] = Wn[i];
    if (tid < DD) sb[tid] = bn[tid];
    int v0 = blockIdx.x * 32;
    for (int i = tid; i < 32 * 36; i += 256) sx[i / 36][i % 36] = node[(size_t)v0 * 36 + i];
    __syncthreads();
    int f = tid & 31;
    int nb = tid >> 5;
    for (int g = 0; g < 4; ++g) {
        int n = nb + 8 * g;
        float acc = sb[f];
        #pragma unroll
        for (int i = 0; i < 36; ++i) acc += sx[n][i] * sW[i * DD + f];
        float y = acc > 0.f ? acc : 0.01f * acc;
        h[(size_t)(v0 + n) * DD + f] = y;
        h0[(size_t)(v0 + n) * DD + f] = y;
    }
}

// ---------------- edge embedding ----------------
__global__ void k_embed_edge(const float* __restrict__ edge, const float* __restrict__ We,
                             const float* __restrict__ be, float* __restrict__ e_h) {
    __shared__ float sW[12 * DD];
    __shared__ float sb[DD];
    __shared__ float sx[32][12];
    int tid = threadIdx.x;
    for (int i = tid; i < 12 * DD; i += 256) sW[i] = We[i];
    if (tid < DD) sb[tid] = be[tid];
    int e0 = blockIdx.x * 32;
    for (int i = tid; i < 32 * 12; i += 256) sx[i / 12][i % 12] = edge[(size_t)e0 * 12 + i];
    __syncthreads();
    int f = tid & 31;
    int nb = tid >> 5;
    for (int g = 0; g < 4; ++g) {
        int n = nb + 8 * g;
        float acc = sb[f];
        #pragma unroll
        for (int i = 0; i < 12; ++i) acc += sx[n][i] * sW[i * DD + f];
        float y = acc > 0.f ? acc : 0.01f * acc;
        e_h[(size_t)(e0 + n) * DD + f] = y;
    }
}

// ---------------- per-layer edge hidden: t = relu(e_h @ eW1 + eb1), (E,64) ----------------
__global__ void k_edge_t(const float* __restrict__ e_h, const float* __restrict__ eW1,
                         const float* __restrict__ eb1, float* __restrict__ t) {
    __shared__ float sW[DD * 64];
    __shared__ float sb[64];
    __shared__ float sx[EPB][DD];
    int tid = threadIdx.x;
    for (int i = tid; i < DD * 64; i += 256) sW[i] = eW1[i];
    if (tid < 64) sb[tid] = eb1[tid];
    int e0 = blockIdx.x * EPB;
    for (int i = tid; i < EPB * DD; i += 256) sx[i >> 5][i & 31] = e_h[(size_t)e0 * DD + i];
    __syncthreads();
    int k = tid & 63;
    int nb = tid >> 6;
    for (int g = 0; g < 4; ++g) {
        int n = nb + 4 * g;
        float acc = sb[k];
        #pragma unroll
        for (int d0 = 0; d0 < DD; ++d0) {
            int d = (k + d0) & 31;
            acc += sx[n][d] * sW[d * 64 + k];
        }
        t[(size_t)(e0 + n) * 64 + k] = fmaxf(acc, 0.f);
    }
}

// ---------------- edge sort by src (once per launch; src is launch-constant) ----------------
__global__ void k_hist(const int* __restrict__ src, int* __restrict__ deg) {
    int e = blockIdx.x * blockDim.x + threadIdx.x;
    if (e < NE) atomicAdd(&deg[src[e]], 1);
}

__global__ void k_scan(const int* __restrict__ deg, int* __restrict__ estart, int* __restrict__ cur) {
    __shared__ int sdeg[SCAN_T * SCAN_C];
    __shared__ int spart[SCAN_T];
    int tid = threadIdx.x;
    for (int i = tid; i < SCAN_T * SCAN_C; i += SCAN_T) sdeg[i] = (i < NV) ? deg[i] : 0;
    __syncthreads();
    int base = tid * SCAN_C;
    int sum = 0;
    for (int j = 0; j < SCAN_C; ++j) sum += sdeg[base + j];
    spart[tid] = sum;
    __syncthreads();
    for (int off = 1; off < SCAN_T; off <<= 1) {
        int v = (tid >= off) ? spart[tid - off] : 0;
        __syncthreads();
        spart[tid] += v;
        __syncthreads();
    }
    int run = spart[tid] - sum;  // exclusive prefix
    for (int j = 0; j < SCAN_C; ++j) {
        int idx = base + j;
        if (idx < NV) { estart[idx] = run; cur[idx] = run; }
        run += sdeg[base + j];
    }
    if (tid == SCAN_T - 1) estart[NV] = run;
}

__global__ void k_scatter(const int* __restrict__ src, int* __restrict__ cur,
                          int* __restrict__ esorted) {
    int e = blockIdx.x * blockDim.x + threadIdx.x;
    if (e < NE) {
        int s = src[e];
        int pos = atomicAdd(&cur[s], 1);
        esorted[pos] = e | ((s & (NBK - 1)) << 24);
    }
}

// ---------------- fused: per-tile A in LDS + edge contraction + scatter ----------------
// Block owns NBK=8 src-nodes. Phase 1: A[n][k][f] = sum_d h[n][d]*eW2[k*1024+d*32+f]
// (h-tile in wave registers, broadcast via readlane; acc[jj][n] register-blocked).
// Phase 2: for each edge with src in tile: msg[f] = bb + sum_k t[e][k]*A[ls][k][f];
// atomicAdd into agg[dst].
__global__ __launch_bounds__(256) void k_fused(const float* __restrict__ h,
        const float* __restrict__ eW2, const float* __restrict__ eb2,
        const float* __restrict__ t, const int* __restrict__ dst,
        const int* __restrict__ estart, const int* __restrict__ esorted,
        float* __restrict__ agg) {
    int v0 = blockIdx.x * NBK;
    __shared__ float sA[NBK][64][32];   // 64 KB
    __shared__ float sbb[NBK][32];
    int tid = threadIdx.x;
    int lane = tid & 63;

    // wave-register h tile: lane l holds h[v0 + (l>>3)][4*(l&7) .. +3]
    float4 hv4 = *(const float4*)(h + (size_t)(v0 + (lane >> 3)) * DD + 4 * (lane & 7));
    float ha[4] = {hv4.x, hv4.y, hv4.z, hv4.w};

    int f = tid & 31;
    int kb = tid >> 5;                  // base kk; thread's jj-th column has kk = kb + 8*jj
    const float* wbase = eW2 + kb * 1024 + f;

    float acc[8][8];                    // [jj][n]
    #pragma unroll
    for (int jj = 0; jj < 8; ++jj)
        #pragma unroll
        for (int n = 0; n < 8; ++n) acc[jj][n] = 0.f;

    #pragma unroll
    for (int d4 = 0; d4 < 8; ++d4) {
        // broadcast h[n][4*d4+dd] for all n,dd (uniform -> SGPR)
        float hs[8][4];
        #pragma unroll
        for (int n = 0; n < 8; ++n)
            #pragma unroll
            for (int dd = 0; dd < 4; ++dd)
                hs[n][dd] = __builtin_bit_cast(float,
                    __builtin_amdgcn_readlane(__builtin_bit_cast(int, ha[dd]), n * 8 + d4));
        #pragma unroll
        for (int jj = 0; jj < 8; ++jj) {
            const float* wp = wbase + jj * 8 * 1024 + d4 * 4 * 32;
            #pragma unroll
            for (int dd = 0; dd < 4; ++dd) {
                float w = wp[dd * 32];
                #pragma unroll
                for (int n = 0; n < 8; ++n) acc[jj][n] = fmaf(hs[n][dd], w, acc[jj][n]);
            }
        }
    }
    #pragma unroll
    for (int jj = 0; jj < 8; ++jj)
        #pragma unroll
        for (int n = 0; n < 8; ++n)
            sA[n][kb + 8 * jj][f] = acc[jj][n];

    // bias factor bb[n][f] = sum_d h[n][d]*eb2[d*32+f]
    {
        int n = tid >> 5;
        float bacc = 0.f;
        #pragma unroll
        for (int d = 0; d < DD; ++d) {
            float hvv = __shfl(ha[d & 3], n * 8 + (d >> 2), 64);
            bacc = fmaf(hvv, eb2[d * 32 + f], bacc);
        }
        sbb[n][f] = bacc;
    }
    __syncthreads();

    // edge phase: half-wave per edge
    int e0 = estart[v0], e1 = estart[v0 + NBK];
    int hw = tid >> 5;     // 0..7
    int ln = tid & 31;
    for (int i = e0 + hw; i < e1; i += 8) {
        int pk = esorted[i];
        int e = pk & 0xFFFFFF;
        int ls = pk >> 24;
        float t0 = t[(size_t)e * 64 + ln];
        float t1 = t[(size_t)e * 64 + 32 + ln];
        int dn = dst[e];
        float m = sbb[ls][ln];
        #pragma unroll
        for (int k = 0; k < 32; ++k) {
            m = fmaf(__shfl(t0, k, 32), sA[ls][k][ln], m);
            m = fmaf(__shfl(t1, k, 32), sA[ls][32 + k][ln], m);
        }
        atomicAdd(&agg[(size_t)dn * DD + ln], m);
    }
}

// ---------------- GRU (vs hidden0) + LayerNorm ----------------
__global__ void k_gru_ln(const float* __restrict__ agg, const float* __restrict__ h0,
                         const float* __restrict__ wih, const float* __restrict__ whh,
                         const float* __restrict__ bih, const float* __restrict__ bhh,
                         const float* __restrict__ lng, const float* __restrict__ lnb,
                         float* __restrict__ h) {
    __shared__ float sWih[96 * DD];
    __shared__ float sWhh[96 * DD];
    __shared__ float sbih[96], sbhh[96], sg[DD], sb[DD];
    __shared__ float sA[32][DD], sH[32][DD];
    int tid = threadIdx.x;
    for (int i = tid; i < 96 * DD; i += 256) { sWih[i] = wih[i]; sWhh[i] = whh[i]; }
    if (tid < 96) { sbih[tid] = bih[tid]; sbhh[tid] = bhh[tid]; }
    if (tid < DD) { sg[tid] = lng[tid]; sb[tid] = lnb[tid]; }
    int v0 = blockIdx.x * 32;
    for (int i = tid; i < 32 * DD; i += 256) {
        sA[i >> 5][i & 31] = fmaxf(agg[(size_t)v0 * DD + i], 0.f);
        sH[i >> 5][i & 31] = h0[(size_t)v0 * DD + i];
    }
    __syncthreads();
    int j = tid & 31;
    int nb = tid >> 5;
    float b_ir = sbih[j], b_iz = sbih[DD + j], b_in = sbih[2 * DD + j];
    float b_hr = sbhh[j], b_hz = sbhh[DD + j], b_hn = sbhh[2 * DD + j];
    float lg = sg[j], lb = sb[j];
    for (int g = 0; g < 4; ++g) {
        int n = nb + 8 * g;
        float gir = b_ir, giz = b_iz, gin = b_in;
        float ghr = b_hr, ghz = b_hz, ghn = b_hn;
        #pragma unroll
        for (int f0 = 0; f0 < DD; ++f0) {
            int f = (j + f0) & 31;
            float a = sA[n][f], hh = sH[n][f];
            gir += a * sWih[j * DD + f];
            giz += a * sWih[(DD + j) * DD + f];
            gin += a * sWih[(2 * DD + j) * DD + f];
            ghr += hh * sWhh[j * DD + f];
            ghz += hh * sWhh[(DD + j) * DD + f];
            ghn += hh * sWhh[(2 * DD + j) * DD + f];
        }
        float r = sigmoidf_(gir + ghr);
        float z = sigmoidf_(giz + ghz);
        float nn = tanhf(gin + r * ghn);
        float hnew = (1.f - z) * nn + z * sH[n][j];
        float mu = hnew;
        #pragma unroll
        for (int o = 16; o; o >>= 1) mu += __shfl_xor(mu, o, 64);
        mu *= (1.f / DD);
        float d = hnew - mu;
        float var = d * d;
        #pragma unroll
        for (int o = 16; o; o >>= 1) var += __shfl_xor(var, o, 64);
        var *= (1.f / DD);
        float inv = rsqrtf(var + 1e-5f);
        h[(size_t)(v0 + n) * DD + j] = d * inv * lg + lb;
    }
}

// ---------------- graph boundaries ----------------
__global__ void k_bounds(const int* __restrict__ n2g, int* __restrict__ gstart) {
    int g = blockIdx.x * blockDim.x + threadIdx.x;
    if (g > NG) return;
    int lo = 0, hi = NV;
    while (lo < hi) {
        int mid = (lo + hi) >> 1;
        if (n2g[mid] < g) lo = mid + 1; else hi = mid;
    }
    gstart[g] = lo;
}

// ---------------- fused Set2Set + prediction MLP ----------------
__global__ void k_s2s(const float* __restrict__ h, const int* __restrict__ gstart,
                      const float* __restrict__ wih, const float* __restrict__ whh,
                      const float* __restrict__ bih, const float* __restrict__ bhh,
                      const float* __restrict__ Wp1, const float* __restrict__ bp1,
                      const float* __restrict__ Wp2, const float* __restrict__ bp2,
                      float* __restrict__ out) {
    int g = blockIdx.x;
    int lane = threadIdx.x;
    int s = gstart[g], e = gstart[g + 1];
    __shared__ float qs[64];
    __shared__ float hhs[DD], ccs[DD], gbuf[128], rr[DD];
    qs[lane] = 0.f;
    if (lane < DD) { hhs[lane] = 0.f; ccs[lane] = 0.f; }
    __syncthreads();
    for (int it = 0; it < S2S; ++it) {
        float g0 = bih[lane] + bhh[lane];
        float g1 = bih[lane + 64] + bhh[lane + 64];
        for (int p = 0; p < 64; ++p) {
            float q = qs[p];
            g0 += q * wih[lane * 64 + p];
            g1 += q * wih[(lane + 64) * 64 + p];
        }
        for (int p = 0; p < DD; ++p) {
            float hp = hhs[p];
            g0 += hp * whh[lane * DD + p];
            g1 += hp * whh[(lane + 64) * DD + p];
        }
        gbuf[lane] = g0;
        gbuf[lane + 64] = g1;
        __syncthreads();
        if (lane < DD) {
            float ii = gbuf[lane], ff = gbuf[DD + lane], gg = gbuf[2 * DD + lane], oo = gbuf[3 * DD + lane];
            float c = sigmoidf_(ff) * ccs[lane] + sigmoidf_(ii) * tanhf(gg);
            ccs[lane] = c;
            hhs[lane] = sigmoidf_(oo) * tanhf(c);
        }
        __syncthreads();
        int f = lane & 31;
        float qf = hhs[f];
        float m = -1e30f, ssum = 0.f;
        for (int v = s; v < e; ++v) {
            float p = h[(size_t)v * DD + f] * qf;
            #pragma unroll
            for (int o = 16; o; o >>= 1) p += __shfl_xor(p, o, 64);
            float nm = fmaxf(m, p);
            ssum = ssum * __expf(m - nm) + __expf(p - nm);
            m = nm;
        }
        float r = 0.f;
        for (int v = s; v < e; ++v) {
            float hv = h[(size_t)v * DD + f];
            float p = hv * qf;
            #pragma unroll
            for (int o = 16; o; o >>= 1) p += __shfl_xor(p, o, 64);
            r += __expf(p - m) * hv;
        }
        r = (e > s) ? (r / ssum) : 0.f;
        if (lane < DD) rr[lane] = r;
        __syncthreads();
        qs[lane] = (lane < DD) ? hhs[lane] : rr[lane - DD];
        __syncthreads();
    }
    int f = lane & 31;
    float u = bp1[f];
    for (int p = 0; p < 64; ++p) u += qs[p] * Wp1[p * DD + f];
    u = fmaxf(u, 0.f);
    float pr = u * Wp2[f];
    #pragma unroll
    for (int o = 16; o; o >>= 1) pr += __shfl_xor(pr, o, 64);
    if (lane == 0) out[g] = pr + bp2[0];
}

extern "C" void kernel_launch(void* const* d_in, const int* in_sizes, int n_in,
                              void* d_out, int out_size, void* d_ws, size_t ws_size,
                              hipStream_t stream) {
    const float* node = (const float*)d_in[0];
    const float* edge = (const float*)d_in[1];
    const int*   src  = (const int*)d_in[2];
    const int*   dst  = (const int*)d_in[3];
    const int*   n2g  = (const int*)d_in[4];
    const float* Wn   = (const float*)d_in[5];
    const float* bn   = (const float*)d_in[6];
    const float* We   = (const float*)d_in[7];
    const float* be   = (const float*)d_in[8];
    const float* eW1  = (const float*)d_in[9];
    const float* eb1  = (const float*)d_in[10];
    const float* eW2  = (const float*)d_in[11];
    const float* eb2  = (const float*)d_in[12];
    const float* gwih = (const float*)d_in[13];
    const float* gwhh = (const float*)d_in[14];
    const float* gbih = (const float*)d_in[15];
    const float* gbhh = (const float*)d_in[16];
    const float* lng  = (const float*)d_in[17];
    const float* lnb  = (const float*)d_in[18];
    const float* lwih = (const float*)d_in[19];
    const float* lwhh = (const float*)d_in[20];
    const float* lbih = (const float*)d_in[21];
    const float* lbhh = (const float*)d_in[22];
    const float* Wp1  = (const float*)d_in[23];
    const float* bp1  = (const float*)d_in[24];
    const float* Wp2  = (const float*)d_in[25];
    const float* bp2  = (const float*)d_in[26];

    float* ws = (float*)d_ws;
    float* h    = ws; ws += (size_t)NV * DD;
    float* h0   = ws; ws += (size_t)NV * DD;
    float* e_h  = ws; ws += (size_t)NE * DD;
    float* t    = ws; ws += (size_t)NE * 64;
    float* agg  = ws; ws += (size_t)NV * DD;
    int* deg     = (int*)ws; ws += NV;
    int* cur     = (int*)ws; ws += NV;
    int* estart  = (int*)ws; ws += (NV + 1);
    int* esorted = (int*)ws; ws += NE;
    int* gstart  = (int*)ws; ws += (NG + 1);

    k_embed_node<<<(NV + 31) / 32, 256, 0, stream>>>(node, Wn, bn, h, h0);
    k_embed_edge<<<(NE + 31) / 32, 256, 0, stream>>>(edge, We, be, e_h);
    k_bounds<<<(NG + 256) / 256, 256, 0, stream>>>(n2g, gstart);

    // edge sort by src (CSR)
    hipMemsetAsync(deg, 0, NV * sizeof(int), stream);
    k_hist<<<(NE + 255) / 256, 256, 0, stream>>>(src, deg);
    k_scan<<<1, SCAN_T, 0, stream>>>(deg, estart, cur);
    k_scatter<<<(NE + 255) / 256, 256, 0, stream>>>(src, cur, esorted);

    for (int l = 0; l < NDEPTH; ++l) {
        k_edge_t<<<NE / EPB, 256, 0, stream>>>(e_h, eW1 + (size_t)l * DD * 64, eb1 + l * 64, t);
        hipMemsetAsync(agg, 0, (size_t)NV * DD * sizeof(float), stream);
        k_fused<<<NV / NBK, 256, 0, stream>>>(h, eW2 + (size_t)l * 64 * 1024, eb2 + l * 1024,
                                              t, dst, estart, esorted, agg);
        k_gru_ln<<<NV / 32, 256, 0, stream>>>(agg, h0,
                                              gwih + (size_t)l * 96 * DD, gwhh + (size_t)l * 96 * DD,
                                              gbih + l * 96, gbhh + l * 96,
                                              lng + l * DD, lnb + l * DD, h);
    }

    k_s2s<<<NG, 64, 0, stream>>>(h, gstart, lwih, lwhh, lbih, lbhh, Wp1, bp1, Wp2, bp2, (float*)d_out);
}

// Round 4
// 917.285 us; speedup vs baseline: 2.4125x; 1.1147x over previous
//
#include <hip/hip_runtime.h>
#include <math.h>

#define NV 20000
#define NE 100000
#define DD 32
#define NG 1000
#define NDEPTH 3
#define S2S 6
#define NBK 8    // src-nodes per block in k_fused
#define EPB 16   // edges per block in k_edge_t
#define CAPN 128 // max nodes of one graph staged in LDS (avg ~20, max ~37 for this data)
#define SCAN_T 256
#define SCAN_C 80  // 256*80 = 20480 >= NV

__device__ __forceinline__ float sigmoidf_(float x) { return 1.0f / (1.0f + __expf(-x)); }

// ---------------- node embedding ----------------
__global__ void k_embed_node(const float* __restrict__ node, const float* __restrict__ Wn,
                             const float* __restrict__ bn, float* __restrict__ h,
                             float* __restrict__ h0) {
    __shared__ float sW[36 * DD];
    __shared__ float sb[DD];
    __shared__ float sx[32][36];
    int tid = threadIdx.x;
    for (int i = tid; i < 36 * DD; i += 256) sW[i] = Wn[i];
    if (tid < DD) sb[tid] = bn[tid];
    int v0 = blockIdx.x * 32;
    for (int i = tid; i < 32 * 36; i += 256) sx[i / 36][i % 36] = node[(size_t)v0 * 36 + i];
    __syncthreads();
    int f = tid & 31;
    int nb = tid >> 5;
    for (int g = 0; g < 4; ++g) {
        int n = nb + 8 * g;
        float acc = sb[f];
        #pragma unroll
        for (int i = 0; i < 36; ++i) acc += sx[n][i] * sW[i * DD + f];
        float y = acc > 0.f ? acc : 0.01f * acc;
        h[(size_t)(v0 + n) * DD + f] = y;
        h0[(size_t)(v0 + n) * DD + f] = y;
    }
}

// ---------------- edge embedding ----------------
__global__ void k_embed_edge(const float* __restrict__ edge, const float* __restrict__ We,
                             const float* __restrict__ be, float* __restrict__ e_h) {
    __shared__ float sW[12 * DD];
    __shared__ float sb[DD];
    __shared__ float sx[32][12];
    int tid = threadIdx.x;
    for (int i = tid; i < 12 * DD; i += 256) sW[i] = We[i];
    if (tid < DD) sb[tid] = be[tid];
    int e0 = blockIdx.x * 32;
    for (int i = tid; i < 32 * 12; i += 256) sx[i / 12][i % 12] = edge[(size_t)e0 * 12 + i];
    __syncthreads();
    int f = tid & 31;
    int nb = tid >> 5;
    for (int g = 0; g < 4; ++g) {
        int n = nb + 8 * g;
        float acc = sb[f];
        #pragma unroll
        for (int i = 0; i < 12; ++i) acc += sx[n][i] * sW[i * DD + f];
        float y = acc > 0.f ? acc : 0.01f * acc;
        e_h[(size_t)(e0 + n) * DD + f] = y;
    }
}

// ---------------- per-layer edge hidden: t = relu(e_h @ eW1 + eb1), (E,64) ----------------
// Also zeroes agg (first 2500 blocks) so the separate memset launch is not needed.
__global__ void k_edge_t(const float* __restrict__ e_h, const float* __restrict__ eW1,
                         const float* __restrict__ eb1, float* __restrict__ t,
                         float* __restrict__ agg) {
    __shared__ float sW[DD * 64];
    __shared__ float sb[64];
    __shared__ float sx[EPB][DD];
    int tid = threadIdx.x;
    if (blockIdx.x < (NV * DD) / 256) agg[(size_t)blockIdx.x * 256 + tid] = 0.f;
    for (int i = tid; i < DD * 64; i += 256) sW[i] = eW1[i];
    if (tid < 64) sb[tid] = eb1[tid];
    int e0 = blockIdx.x * EPB;
    for (int i = tid; i < EPB * DD; i += 256) sx[i >> 5][i & 31] = e_h[(size_t)e0 * DD + i];
    __syncthreads();
    int k = tid & 63;
    int nb = tid >> 6;
    for (int g = 0; g < 4; ++g) {
        int n = nb + 4 * g;
        float acc = sb[k];
        #pragma unroll
        for (int d0 = 0; d0 < DD; ++d0) {
            int d = (k + d0) & 31;
            acc += sx[n][d] * sW[d * 64 + k];
        }
        t[(size_t)(e0 + n) * 64 + k] = fmaxf(acc, 0.f);
    }
}

// ---------------- edge sort by src (once per launch; src is launch-constant) ----------------
__global__ void k_hist(const int* __restrict__ src, int* __restrict__ deg) {
    int e = blockIdx.x * blockDim.x + threadIdx.x;
    if (e < NE) atomicAdd(&deg[src[e]], 1);
}

__global__ void k_scan(const int* __restrict__ deg, int* __restrict__ estart, int* __restrict__ cur) {
    __shared__ int sdeg[SCAN_T * SCAN_C];
    __shared__ int spart[SCAN_T];
    int tid = threadIdx.x;
    for (int i = tid; i < SCAN_T * SCAN_C; i += SCAN_T) sdeg[i] = (i < NV) ? deg[i] : 0;
    __syncthreads();
    int base = tid * SCAN_C;
    int sum = 0;
    for (int j = 0; j < SCAN_C; ++j) sum += sdeg[base + j];
    spart[tid] = sum;
    __syncthreads();
    for (int off = 1; off < SCAN_T; off <<= 1) {
        int v = (tid >= off) ? spart[tid - off] : 0;
        __syncthreads();
        spart[tid] += v;
        __syncthreads();
    }
    int run = spart[tid] - sum;  // exclusive prefix
    for (int j = 0; j < SCAN_C; ++j) {
        int idx = base + j;
        if (idx < NV) { estart[idx] = run; cur[idx] = run; }
        run += sdeg[base + j];
    }
    if (tid == SCAN_T - 1) estart[NV] = run;
}

__global__ void k_scatter(const int* __restrict__ src, int* __restrict__ cur,
                          int* __restrict__ esorted) {
    int e = blockIdx.x * blockDim.x + threadIdx.x;
    if (e < NE) {
        int s = src[e];
        int pos = atomicAdd(&cur[s], 1);
        esorted[pos] = e | ((s & (NBK - 1)) << 24);
    }
}

// ---------------- fused: per-tile A in LDS + edge contraction + scatter ----------------
__global__ __launch_bounds__(256) void k_fused(const float* __restrict__ h,
        const float* __restrict__ eW2, const float* __restrict__ eb2,
        const float* __restrict__ t, const int* __restrict__ dst,
        const int* __restrict__ estart, const int* __restrict__ esorted,
        float* __restrict__ agg) {
    int v0 = blockIdx.x * NBK;
    __shared__ float sA[NBK][64][32];   // 64 KB
    __shared__ float sbb[NBK][32];
    int tid = threadIdx.x;
    int lane = tid & 63;

    // wave-register h tile: lane l holds h[v0 + (l>>3)][4*(l&7) .. +3]
    float4 hv4 = *(const float4*)(h + (size_t)(v0 + (lane >> 3)) * DD + 4 * (lane & 7));
    float ha[4] = {hv4.x, hv4.y, hv4.z, hv4.w};

    int f = tid & 31;
    int kb = tid >> 5;
    const float* wbase = eW2 + kb * 1024 + f;

    float acc[8][8];                    // [jj][n]
    #pragma unroll
    for (int jj = 0; jj < 8; ++jj)
        #pragma unroll
        for (int n = 0; n < 8; ++n) acc[jj][n] = 0.f;

    #pragma unroll
    for (int d4 = 0; d4 < 8; ++d4) {
        float hs[8][4];
        #pragma unroll
        for (int n = 0; n < 8; ++n)
            #pragma unroll
            for (int dd = 0; dd < 4; ++dd)
                hs[n][dd] = __builtin_bit_cast(float,
                    __builtin_amdgcn_readlane(__builtin_bit_cast(int, ha[dd]), n * 8 + d4));
        #pragma unroll
        for (int jj = 0; jj < 8; ++jj) {
            const float* wp = wbase + jj * 8 * 1024 + d4 * 4 * 32;
            #pragma unroll
            for (int dd = 0; dd < 4; ++dd) {
                float w = wp[dd * 32];
                #pragma unroll
                for (int n = 0; n < 8; ++n) acc[jj][n] = fmaf(hs[n][dd], w, acc[jj][n]);
            }
        }
    }
    #pragma unroll
    for (int jj = 0; jj < 8; ++jj)
        #pragma unroll
        for (int n = 0; n < 8; ++n)
            sA[n][kb + 8 * jj][f] = acc[jj][n];

    {
        int n = tid >> 5;
        float bacc = 0.f;
        #pragma unroll
        for (int d = 0; d < DD; ++d) {
            float hvv = __shfl(ha[d & 3], n * 8 + (d >> 2), 64);
            bacc = fmaf(hvv, eb2[d * 32 + f], bacc);
        }
        sbb[n][f] = bacc;
    }
    __syncthreads();

    // edge phase: half-wave per edge
    int e0 = estart[v0], e1 = estart[v0 + NBK];
    int hw = tid >> 5;
    int ln = tid & 31;
    #pragma unroll 2
    for (int i = e0 + hw; i < e1; i += 8) {
        int pk = esorted[i];
        int e = pk & 0xFFFFFF;
        int ls = pk >> 24;
        float t0 = t[(size_t)e * 64 + ln];
        float t1 = t[(size_t)e * 64 + 32 + ln];
        int dn = dst[e];
        float m = sbb[ls][ln];
        #pragma unroll
        for (int k = 0; k < 32; ++k) {
            m = fmaf(__shfl(t0, k, 32), sA[ls][k][ln], m);
            m = fmaf(__shfl(t1, k, 32), sA[ls][32 + k][ln], m);
        }
        atomicAdd(&agg[(size_t)dn * DD + ln], m);
    }
}

// ---------------- GRU (vs hidden0) + LayerNorm ----------------
__global__ void k_gru_ln(const float* __restrict__ agg, const float* __restrict__ h0,
                         const float* __restrict__ wih, const float* __restrict__ whh,
                         const float* __restrict__ bih, const float* __restrict__ bhh,
                         const float* __restrict__ lng, const float* __restrict__ lnb,
                         float* __restrict__ h) {
    __shared__ float sWih[96 * DD];
    __shared__ float sWhh[96 * DD];
    __shared__ float sbih[96], sbhh[96], sg[DD], sb[DD];
    __shared__ float sA[32][DD], sH[32][DD];
    int tid = threadIdx.x;
    for (int i = tid; i < 96 * DD; i += 256) { sWih[i] = wih[i]; sWhh[i] = whh[i]; }
    if (tid < 96) { sbih[tid] = bih[tid]; sbhh[tid] = bhh[tid]; }
    if (tid < DD) { sg[tid] = lng[tid]; sb[tid] = lnb[tid]; }
    int v0 = blockIdx.x * 32;
    for (int i = tid; i < 32 * DD; i += 256) {
        sA[i >> 5][i & 31] = fmaxf(agg[(size_t)v0 * DD + i], 0.f);
        sH[i >> 5][i & 31] = h0[(size_t)v0 * DD + i];
    }
    __syncthreads();
    int j = tid & 31;
    int nb = tid >> 5;
    float b_ir = sbih[j], b_iz = sbih[DD + j], b_in = sbih[2 * DD + j];
    float b_hr = sbhh[j], b_hz = sbhh[DD + j], b_hn = sbhh[2 * DD + j];
    float lg = sg[j], lb = sb[j];
    for (int g = 0; g < 4; ++g) {
        int n = nb + 8 * g;
        float gir = b_ir, giz = b_iz, gin = b_in;
        float ghr = b_hr, ghz = b_hz, ghn = b_hn;
        #pragma unroll
        for (int f0 = 0; f0 < DD; ++f0) {
            int f = (j + f0) & 31;
            float a = sA[n][f], hh = sH[n][f];
            gir += a * sWih[j * DD + f];
            giz += a * sWih[(DD + j) * DD + f];
            gin += a * sWih[(2 * DD + j) * DD + f];
            ghr += hh * sWhh[j * DD + f];
            ghz += hh * sWhh[(DD + j) * DD + f];
            ghn += hh * sWhh[(2 * DD + j) * DD + f];
        }
        float r = sigmoidf_(gir + ghr);
        float z = sigmoidf_(giz + ghz);
        float nn = tanhf(gin + r * ghn);
        float hnew = (1.f - z) * nn + z * sH[n][j];
        float mu = hnew;
        #pragma unroll
        for (int o = 16; o; o >>= 1) mu += __shfl_xor(mu, o, 64);
        mu *= (1.f / DD);
        float d = hnew - mu;
        float var = d * d;
        #pragma unroll
        for (int o = 16; o; o >>= 1) var += __shfl_xor(var, o, 64);
        var *= (1.f / DD);
        float inv = rsqrtf(var + 1e-5f);
        h[(size_t)(v0 + n) * DD + j] = d * inv * lg + lb;
    }
}

// ---------------- graph boundaries ----------------
__global__ void k_bounds(const int* __restrict__ n2g, int* __restrict__ gstart) {
    int g = blockIdx.x * blockDim.x + threadIdx.x;
    if (g > NG) return;
    int lo = 0, hi = NV;
    while (lo < hi) {
        int mid = (lo + hi) >> 1;
        if (n2g[mid] < g) lo = mid + 1; else hi = mid;
    }
    gstart[g] = lo;
}

// ---------------- fused Set2Set + prediction MLP: 256 threads per graph ----------------
__global__ __launch_bounds__(256) void k_s2s(const float* __restrict__ h,
                      const int* __restrict__ gstart,
                      const float* __restrict__ wih, const float* __restrict__ whh,
                      const float* __restrict__ bih, const float* __restrict__ bhh,
                      const float* __restrict__ Wp1, const float* __restrict__ bp1,
                      const float* __restrict__ Wp2, const float* __restrict__ bp2,
                      float* __restrict__ attbuf, float* __restrict__ out) {
    int g = blockIdx.x, tid = threadIdx.x;
    int s = gstart[g], e = gstart[g + 1], cnt = e - s;
    bool inlds = (cnt <= CAPN);
    __shared__ float sh[CAPN * 33];       // stride 33: conflict-free row+col access
    __shared__ float qs[64], shh[32], scc[32], gbuf[128];
    __shared__ float satt[256];
    __shared__ float red[4];
    __shared__ float rpart[8][32];
    if (inlds) {
        for (int idx = tid; idx < cnt * 32; idx += 256) {
            int v = idx >> 5, f = idx & 31;
            sh[v * 33 + f] = h[(size_t)(s + v) * 32 + f];
        }
    }
    if (tid < 64) qs[tid] = 0.f;
    if (tid < 32) { shh[tid] = 0.f; scc[tid] = 0.f; }
    __syncthreads();
    for (int it = 0; it < S2S; ++it) {
        // LSTM gates: thread j<128 computes gate j (float4 weight loads, pipelined)
        if (tid < 128) {
            float gv = bih[tid] + bhh[tid];
            const float4* w4 = (const float4*)(wih + tid * 64);
            #pragma unroll
            for (int i = 0; i < 16; ++i) {
                float4 w = w4[i];
                gv += qs[4 * i] * w.x + qs[4 * i + 1] * w.y + qs[4 * i + 2] * w.z + qs[4 * i + 3] * w.w;
            }
            const float4* u4 = (const float4*)(whh + tid * 32);
            #pragma unroll
            for (int i = 0; i < 8; ++i) {
                float4 w = u4[i];
                gv += shh[4 * i] * w.x + shh[4 * i + 1] * w.y + shh[4 * i + 2] * w.z + shh[4 * i + 3] * w.w;
            }
            gbuf[tid] = gv;
        }
        __syncthreads();
        if (tid < 32) {
            float ii = gbuf[tid], ff = gbuf[32 + tid], gg = gbuf[64 + tid], oo = gbuf[96 + tid];
            float c = sigmoidf_(ff) * scc[tid] + sigmoidf_(ii) * tanhf(gg);
            scc[tid] = c;
            float hv = sigmoidf_(oo) * tanhf(c);
            shh[tid] = hv;
            qs[tid] = hv;
        }
        __syncthreads();
        // attention scores: one thread per node
        float pmax = -1e30f;
        if (inlds) {
            float a = -1e30f;
            if (tid < cnt) {
                float acc = 0.f;
                #pragma unroll
                for (int f = 0; f < 32; ++f) acc += sh[tid * 33 + f] * shh[f];
                a = acc;
            }
            satt[tid] = a;
            pmax = a;
        } else {
            for (int v = tid; v < cnt; v += 256) {
                float acc = 0.f;
                const float* hp = h + (size_t)(s + v) * 32;
                #pragma unroll
                for (int f = 0; f < 32; ++f) acc += hp[f] * shh[f];
                attbuf[s + v] = acc;
                pmax = fmaxf(pmax, acc);
            }
        }
        #pragma unroll
        for (int o = 32; o; o >>= 1) pmax = fmaxf(pmax, __shfl_xor(pmax, o, 64));
        if ((tid & 63) == 0) red[tid >> 6] = pmax;
        __syncthreads();
        float m = fmaxf(fmaxf(red[0], red[1]), fmaxf(red[2], red[3]));
        // exp & sum
        float psum = 0.f;
        if (inlds) {
            if (tid < cnt) { float exv = __expf(satt[tid] - m); satt[tid] = exv; psum = exv; }
        } else {
            for (int v = tid; v < cnt; v += 256) {
                float exv = __expf(attbuf[s + v] - m); attbuf[s + v] = exv; psum += exv;
            }
        }
        #pragma unroll
        for (int o = 32; o; o >>= 1) psum += __shfl_xor(psum, o, 64);
        __syncthreads();   // red reads (m) done before overwrite
        if ((tid & 63) == 0) red[tid >> 6] = psum;
        __syncthreads();
        float denom = red[0] + red[1] + red[2] + red[3];
        // weighted read: 8 v-chunks x 32 f
        int f = tid & 31, vc = tid >> 5;
        float racc = 0.f;
        if (inlds) {
            for (int v = vc; v < cnt; v += 8) racc += satt[v] * sh[v * 33 + f];
        } else {
            for (int v = vc; v < cnt; v += 8) racc += attbuf[s + v] * h[(size_t)(s + v) * 32 + f];
        }
        rpart[vc][f] = racc;
        __syncthreads();
        if (tid < 32) {
            float r = 0.f;
            #pragma unroll
            for (int c2 = 0; c2 < 8; ++c2) r += rpart[c2][tid];
            qs[32 + tid] = (cnt > 0) ? (r / denom) : 0.f;
        }
        __syncthreads();
    }
    // prediction MLP
    if (tid < 32) {
        float u = bp1[tid];
        #pragma unroll
        for (int p = 0; p < 64; ++p) u += qs[p] * Wp1[p * 32 + tid];
        u = fmaxf(u, 0.f);
        float pr = u * Wp2[tid];
        #pragma unroll
        for (int o = 16; o; o >>= 1) pr += __shfl_xor(pr, o, 64);
        if (tid == 0) out[g] = pr + bp2[0];
    }
}

extern "C" void kernel_launch(void* const* d_in, const int* in_sizes, int n_in,
                              void* d_out, int out_size, void* d_ws, size_t ws_size,
                              hipStream_t stream) {
    const float* node = (const float*)d_in[0];
    const float* edge = (const float*)d_in[1];
    const int*   src  = (const int*)d_in[2];
    const int*   dst  = (const int*)d_in[3];
    const int*   n2g  = (const int*)d_in[4];
    const float* Wn   = (const float*)d_in[5];
    const float* bn   = (const float*)d_in[6];
    const float* We   = (const float*)d_in[7];
    const float* be   = (const float*)d_in[8];
    const float* eW1  = (const float*)d_in[9];
    const float* eb1  = (const float*)d_in[10];
    const float* eW2  = (const float*)d_in[11];
    const float* eb2  = (const float*)d_in[12];
    const float* gwih = (const float*)d_in[13];
    const float* gwhh = (const float*)d_in[14];
    const float* gbih = (const float*)d_in[15];
    const float* gbhh = (const float*)d_in[16];
    const float* lng  = (const float*)d_in[17];
    const float* lnb  = (const float*)d_in[18];
    const float* lwih = (const float*)d_in[19];
    const float* lwhh = (const float*)d_in[20];
    const float* lbih = (const float*)d_in[21];
    const float* lbhh = (const float*)d_in[22];
    const float* Wp1  = (const float*)d_in[23];
    const float* bp1  = (const float*)d_in[24];
    const float* Wp2  = (const float*)d_in[25];
    const float* bp2  = (const float*)d_in[26];

    float* ws = (float*)d_ws;
    float* h    = ws; ws += (size_t)NV * DD;
    float* h0   = ws; ws += (size_t)NV * DD;
    float* e_h  = ws; ws += (size_t)NE * DD;
    float* t    = ws; ws += (size_t)NE * 64;
    float* agg  = ws; ws += (size_t)NV * DD;
    float* attbuf = ws; ws += NV;
    int* deg     = (int*)ws; ws += NV;
    int* cur     = (int*)ws; ws += NV;
    int* estart  = (int*)ws; ws += (NV + 1);
    int* esorted = (int*)ws; ws += NE;
    int* gstart  = (int*)ws; ws += (NG + 1);

    k_embed_node<<<(NV + 31) / 32, 256, 0, stream>>>(node, Wn, bn, h, h0);
    k_embed_edge<<<(NE + 31) / 32, 256, 0, stream>>>(edge, We, be, e_h);
    k_bounds<<<(NG + 256) / 256, 256, 0, stream>>>(n2g, gstart);

    // edge sort by src (CSR)
    hipMemsetAsync(deg, 0, NV * sizeof(int), stream);
    k_hist<<<(NE + 255) / 256, 256, 0, stream>>>(src, deg);
    k_scan<<<1, SCAN_T, 0, stream>>>(deg, estart, cur);
    k_scatter<<<(NE + 255) / 256, 256, 0, stream>>>(src, cur, esorted);

    for (int l = 0; l < NDEPTH; ++l) {
        k_edge_t<<<NE / EPB, 256, 0, stream>>>(e_h, eW1 + (size_t)l * DD * 64, eb1 + l * 64, t, agg);
        k_fused<<<NV / NBK, 256, 0, stream>>>(h, eW2 + (size_t)l * 64 * 1024, eb2 + l * 1024,
                                              t, dst, estart, esorted, agg);
        k_gru_ln<<<NV / 32, 256, 0, stream>>>(agg, h0,
                                              gwih + (size_t)l * 96 * DD, gwhh + (size_t)l * 96 * DD,
                                              gbih + l * 96, gbhh + l * 96,
                                              lng + l * DD, lnb + l * DD, h);
    }

    k_s2s<<<NG, 256, 0, stream>>>(h, gstart, lwih, lwhh, lbih, lbhh, Wp1, bp1, Wp2, bp2,
                                  attbuf, (float*)d_out);
}